// Round 5
// baseline (140.420 us; speedup 1.0000x reference)
//
#include <hip/hip_runtime.h>
#include <stdint.h>

// Problem dims
#define TDIM 4096
#define HDIM 2048   // N and K of the GEMM

// GEMM tile
#define BM 256
#define BN 128
#define BK 64
#define NKT (HDIM / BK)   // 32
// LDS: per buffer = A region (272 rows = 34 groups of 8 rows, 1KB/group)
//      + B region (128 rows = 16 groups), 128B per row (BK=64 bf16)
#define AREG  34816
#define PERBUF 51200
#define NBUF 3            // triple buffer: prefetch distance 2, never drain
#define SSTR   132        // S-tile row stride in elements (breaks bank conflicts)

typedef short short8 __attribute__((ext_vector_type(8)));
typedef float f32x4 __attribute__((ext_vector_type(4)));

__device__ __forceinline__ uint16_t f2bf(float f) {
  uint32_t u = __builtin_bit_cast(uint32_t, f);
  u += 0x7fffu + ((u >> 16) & 1u);          // round-to-nearest-even
  return (uint16_t)(u >> 16);
}
__device__ __forceinline__ float bf2f(uint32_t h) {   // low 16 bits used
  uint32_t u = h << 16;
  return __builtin_bit_cast(float, u);
}

__device__ __forceinline__ void async_copy16(const void* gsrc, void* ldst) {
  __builtin_amdgcn_global_load_lds(
      (const __attribute__((address_space(1))) uint32_t*)gsrc,
      (__attribute__((address_space(3))) uint32_t*)ldst,
      16, 0, 0);
}

// ------------- prep: cvt x (fp32->bf16) + transpose/cvt B -> Bt -------------
__global__ void prep(const float* __restrict__ x, const float* __restrict__ B,
                     uint16_t* __restrict__ xb, uint16_t* __restrict__ Bt) {
  __shared__ uint16_t tile[64][70];   // stride 70: even (uint2-aligned), ~2-way banks
  const int t = threadIdx.x;
  if (blockIdx.x < 4096) {
    size_t i = ((size_t)blockIdx.x * 256 + t) * 8;
    float4 v0 = *(const float4*)(x + i);
    float4 v1 = *(const float4*)(x + i + 4);
    union { uint16_t h[8]; uint4 v; } o;
    o.h[0] = f2bf(v0.x); o.h[1] = f2bf(v0.y); o.h[2] = f2bf(v0.z); o.h[3] = f2bf(v0.w);
    o.h[4] = f2bf(v1.x); o.h[5] = f2bf(v1.y); o.h[6] = f2bf(v1.z); o.h[7] = f2bf(v1.w);
    *(uint4*)(xb + i) = o.v;
  } else {
    const int bid = blockIdx.x - 4096;
    const int n0 = (bid & 31) * 64;
    const int k0 = (bid >> 5) * 64;
    {
      const int r  = t >> 4;
      const int c4 = (t & 15) * 4;
#pragma unroll
      for (int i = 0; i < 4; ++i) {
        int rr = r + i * 16;
        float4 v = *(const float4*)&B[(size_t)(k0 + rr) * HDIM + n0 + c4];
        union { uint16_t h[4]; uint2 u; } o;
        o.h[0] = f2bf(v.x); o.h[1] = f2bf(v.y); o.h[2] = f2bf(v.z); o.h[3] = f2bf(v.w);
        *(uint2*)&tile[rr][c4] = o.u;
      }
    }
    __syncthreads();
    {
      // 16B stores: 8 threads per Bt row, 128B contiguous per row
      const int nr8 = t >> 3;           // 0..31
      const int kc8 = (t & 7) * 8;      // 0..56
#pragma unroll
      for (int i = 0; i < 2; ++i) {
        int nr = nr8 + i * 32;
        union { uint16_t h[8]; uint4 v; } o;
#pragma unroll
        for (int j = 0; j < 8; ++j) o.h[j] = tile[kc8 + j][nr];
        *(uint4*)&Bt[(size_t)(n0 + nr) * HDIM + k0 + kc8] = o.v;
      }
    }
  }
}

// --------- fused GEMM + causal exp-decay recurrence (scan) ---------
// S[t][n] = sum_k A[t][k]*Bt[n][k]; out[t][h] = S[t][h] + a[h]*out[t-1][h].
// FINDING (R0-R4): the 2-phase {reads -> lgkm -> MFMA} barrier-locked
// schedule serializes the LDS port (~24us) and MFMA pipe (~14us) per CU:
// all variants pinned at ~48us regardless of traffic/occupancy/waves.
// FIX (m201/m196 pattern): 4 phases per K-tile, each {ds_read subtile |
// stage chunk | barrier | lgkm | setprio MFMA quadrant}; reads sit before
// the barrier so they overlap OTHER waves' MFMA clusters (role-skew).
// Triple-buffered LDS, prefetch distance 2 tiles: steady-state vmcnt(6/7)
// leaves tile kt+2 in flight -- never drains.  P3 completes lgkm BEFORE
// its barrier (closes read-vs-restage race: buf (kt+2)%3 == (kt-1)%3).
// 512 thr = 8 waves (4Mx2N), 64x64/wave; BM=256: B staged once/256 rows;
// grid 256 = 1 block/CU.  BK=64: 128B rows + XOR-8 swizzle, conflict-free.
// 16 warmup rows on waves 0,1; in-LDS S-tile scan epilogue (|a| <= 2^-5).
__global__ __launch_bounds__(512, 2) void gemm_scan(
    const uint16_t* __restrict__ A, const uint16_t* __restrict__ Bt,
    const float* __restrict__ a, float* __restrict__ out) {
  __shared__ __align__(16) char lds[NBUF * PERBUF];   // 153600 <= 160KiB

  const int tid  = threadIdx.x;
  const int lane = tid & 63;
  const int wave = tid >> 6;            // 0..7
  const int wm = (wave >> 1) * 64;      // wave row offset {0,64,128,192}
  const int wn = (wave & 1) * 64;       // wave col offset {0,64}

  // XCD-chunked bijective swizzle: 256 blocks, 8 XCDs, 32 consecutive
  // logical tiles per XCD -> the 16 blocks sharing an A-panel colocate.
  const int flat = blockIdx.y * gridDim.x + blockIdx.x;
  const int logi = (flat & 7) * 32 + (flat >> 3);
  const int m0 = (logi >> 4) * BM;      // 16 m-blocks
  const int n0 = (logi & 15) * BN;      // 16 n-blocks

  f32x4 acc[4][4] = {};
  f32x4 accw[4] = {};                   // warmup rows (waves 0,1 only)

  // staging: one instr = 8 rows x 128B (1KB); lane l: row lr=l>>3, slot l&7,
  // fetches global chunk (l&7)^lr -> LDS slot c of row r holds chunk c^(r&7)
  const int lr = lane >> 3;             // 0..7
  const int gc = (lane & 7) ^ lr;       // swizzled 16B chunk to fetch

  const int fr = lane & 15;
  const int fq = lane >> 4;             // 0..3

  // A: 34 groups of 8 rows (t in [m0-16, m0+256)); wave w takes g=4w..4w+3,
  // waves 0,1 also g=32,33 (issued in P0).  B: 16 groups; wave w takes
  // 2w,2w+1 (issued in P2).  Per-wave per-tile loads: 7 (w<2) / 6.
  auto issue_A = [&](int kt2, int boff) {
    size_t koff = (size_t)kt2 * (BK * 2);
    char* dst = lds + boff;
#pragma unroll
    for (int i = 0; i < 4; ++i) {
      int g = wave * 4 + i;
      int row = m0 - 16 + g * 8 + lr;
      if (row < 0) row = 0;             // m0==0: garbage rows, never used
      async_copy16((const char*)A + ((size_t)row * HDIM + gc * 8) * 2 + koff,
                   dst + g * 1024);
    }
    if (wave < 2) {
      int g = 32 + wave;
      int row = m0 - 16 + g * 8 + lr;   // rows m0+240..m0+255: always valid
      async_copy16((const char*)A + ((size_t)row * HDIM + gc * 8) * 2 + koff,
                   dst + g * 1024);
    }
  };
  auto issue_B = [&](int kt2, int boff) {
    size_t koff = (size_t)kt2 * (BK * 2);
    char* dst = lds + boff;
#pragma unroll
    for (int i = 0; i < 2; ++i) {
      int g = wave * 2 + i;
      int row = n0 + g * 8 + lr;
      async_copy16((const char*)Bt + ((size_t)row * HDIM + gc * 8) * 2 + koff,
                   dst + AREG + g * 1024);
    }
  };

  // prologue: stage tiles 0 and 1; wait tile 0 (leave tile 1 in flight)
  issue_A(0, 0);          issue_B(0, 0);
  issue_A(1, PERBUF);     issue_B(1, PERBUF);
  if (wave < 2) asm volatile("s_waitcnt vmcnt(7)" ::: "memory");
  else          asm volatile("s_waitcnt vmcnt(6)" ::: "memory");
  asm volatile("s_barrier" ::: "memory");

  int bc = 0;               // buffer of tile kt
  int bs = 2 * PERBUF;      // buffer of tile kt+2 (stage target)
  for (int kt = 0; kt < NKT; ++kt) {
    const char* base = lds + bc;
    const bool pf = (kt + 2 < NKT);

    short8 af[4], bfr[2], aw;

    // ---- P0: s=0 frags (A all, B in=0,1) | stage A(kt+2) | MFMA Q(s0,n01)
#pragma unroll
    for (int im = 0; im < 4; ++im)
      af[im] = *(const short8*)(base + (16 + wm + im * 16 + fr) * 128 +
                                ((fq ^ (fr & 7)) * 16));
#pragma unroll
    for (int in = 0; in < 2; ++in)
      bfr[in] = *(const short8*)(base + AREG + (wn + in * 16 + fr) * 128 +
                                 ((fq ^ (fr & 7)) * 16));
    aw = af[0];
    if (wave < 2)
      aw = *(const short8*)(base + fr * 128 + ((fq ^ (fr & 7)) * 16));
    if (pf) issue_A(kt + 2, bs);
    asm volatile("s_barrier" ::: "memory");
    asm volatile("s_waitcnt lgkmcnt(0)" ::: "memory");
    __builtin_amdgcn_sched_barrier(0);
    __builtin_amdgcn_s_setprio(1);
#pragma unroll
    for (int im = 0; im < 4; ++im)
#pragma unroll
      for (int in = 0; in < 2; ++in)
        acc[im][in] = __builtin_amdgcn_mfma_f32_16x16x32_bf16(
            af[im], bfr[in], acc[im][in], 0, 0, 0);
    if (wave < 2) {
#pragma unroll
      for (int in = 0; in < 2; ++in)
        accw[in] = __builtin_amdgcn_mfma_f32_16x16x32_bf16(
            aw, bfr[in], accw[in], 0, 0, 0);
    }
    __builtin_amdgcn_s_setprio(0);

    // ---- P1: s=0 frags (B in=2,3) | MFMA Q(s0,n23)  [af, aw stay live]
#pragma unroll
    for (int in = 0; in < 2; ++in)
      bfr[in] = *(const short8*)(base + AREG + (wn + (in + 2) * 16 + fr) * 128 +
                                 ((fq ^ (fr & 7)) * 16));
    asm volatile("s_barrier" ::: "memory");
    asm volatile("s_waitcnt lgkmcnt(0)" ::: "memory");
    __builtin_amdgcn_sched_barrier(0);
    __builtin_amdgcn_s_setprio(1);
#pragma unroll
    for (int im = 0; im < 4; ++im)
#pragma unroll
      for (int in = 0; in < 2; ++in)
        acc[im][in + 2] = __builtin_amdgcn_mfma_f32_16x16x32_bf16(
            af[im], bfr[in], acc[im][in + 2], 0, 0, 0);
    if (wave < 2) {
#pragma unroll
      for (int in = 0; in < 2; ++in)
        accw[in + 2] = __builtin_amdgcn_mfma_f32_16x16x32_bf16(
            aw, bfr[in], accw[in + 2], 0, 0, 0);
    }
    __builtin_amdgcn_s_setprio(0);

    // ---- P2: s=1 frags (A all, B in=0,1) | stage B(kt+2) | MFMA Q(s1,n01)
#pragma unroll
    for (int im = 0; im < 4; ++im)
      af[im] = *(const short8*)(base + (16 + wm + im * 16 + fr) * 128 +
                                (((4 + fq) ^ (fr & 7)) * 16));
#pragma unroll
    for (int in = 0; in < 2; ++in)
      bfr[in] = *(const short8*)(base + AREG + (wn + in * 16 + fr) * 128 +
                                 (((4 + fq) ^ (fr & 7)) * 16));
    if (wave < 2)
      aw = *(const short8*)(base + fr * 128 + (((4 + fq) ^ (fr & 7)) * 16));
    if (pf) issue_B(kt + 2, bs);
    asm volatile("s_barrier" ::: "memory");
    asm volatile("s_waitcnt lgkmcnt(0)" ::: "memory");
    __builtin_amdgcn_sched_barrier(0);
    __builtin_amdgcn_s_setprio(1);
#pragma unroll
    for (int im = 0; im < 4; ++im)
#pragma unroll
      for (int in = 0; in < 2; ++in)
        acc[im][in] = __builtin_amdgcn_mfma_f32_16x16x32_bf16(
            af[im], bfr[in], acc[im][in], 0, 0, 0);
    if (wave < 2) {
#pragma unroll
      for (int in = 0; in < 2; ++in)
        accw[in] = __builtin_amdgcn_mfma_f32_16x16x32_bf16(
            aw, bfr[in], accw[in], 0, 0, 0);
    }
    __builtin_amdgcn_s_setprio(0);

    // ---- P3: s=1 frags (B in=2,3) | counted vmcnt | MFMA Q(s1,n23)
    // lgkm BEFORE the barrier: all this wave's reads of buf bc are complete
    // when it crosses, so P0(kt+1)'s stage into bs'=(kt-1)%3 can't race.
#pragma unroll
    for (int in = 0; in < 2; ++in)
      bfr[in] = *(const short8*)(base + AREG + (wn + (in + 2) * 16 + fr) * 128 +
                                 (((4 + fq) ^ (fr & 7)) * 16));
    asm volatile("s_waitcnt lgkmcnt(0)" ::: "memory");
    __builtin_amdgcn_sched_barrier(0);
    if (pf) {
      // leave tile kt+2's own loads (7 / 6) in flight; tile kt+1 drained
      if (wave < 2) asm volatile("s_waitcnt vmcnt(7)" ::: "memory");
      else          asm volatile("s_waitcnt vmcnt(6)" ::: "memory");
    } else {
      asm volatile("s_waitcnt vmcnt(0)" ::: "memory");
    }
    asm volatile("s_barrier" ::: "memory");
    __builtin_amdgcn_s_setprio(1);
#pragma unroll
    for (int im = 0; im < 4; ++im)
#pragma unroll
      for (int in = 0; in < 2; ++in)
        acc[im][in + 2] = __builtin_amdgcn_mfma_f32_16x16x32_bf16(
            af[im], bfr[in], acc[im][in + 2], 0, 0, 0);
    if (wave < 2) {
#pragma unroll
      for (int in = 0; in < 2; ++in)
        accw[in + 2] = __builtin_amdgcn_mfma_f32_16x16x32_bf16(
            aw, bfr[in], accw[in + 2], 0, 0, 0);
    }
    __builtin_amdgcn_s_setprio(0);

    bc += PERBUF; if (bc == NBUF * PERBUF) bc = 0;
    bs += PERBUF; if (bs == NBUF * PERBUF) bs = 0;
  }

  __syncthreads();   // all reads done before S-tile overwrite

  // ---- epilogue: S-tile (272 x 128, bf16, stride 132) into LDS ----
  uint16_t* Sl = (uint16_t*)lds;
#pragma unroll
  for (int im = 0; im < 4; ++im)
#pragma unroll
    for (int in = 0; in < 4; ++in)
#pragma unroll
      for (int r = 0; r < 4; ++r)
        Sl[(16 + wm + im * 16 + fq * 4 + r) * SSTR + wn + in * 16 + fr] =
            f2bf(acc[im][in][r]);
  if (wave < 2) {
#pragma unroll
    for (int in = 0; in < 4; ++in)
#pragma unroll
      for (int r = 0; r < 4; ++r)
        Sl[(fq * 4 + r) * SSTR + wn + in * 16 + fr] = f2bf(accw[in][r]);
  }
  __syncthreads();

  // ---- scan: 4 threads per column, 64 t-steps each, 16-step warmup ----
  const int col   = tid & 127;
  const int chunk = tid >> 7;           // 0..3
  const float av  = a[n0 + col];
  float h = 0.f;
  if (!(m0 == 0 && chunk == 0)) {
#pragma unroll
    for (int i = 0; i < 16; ++i)
      h = av * h + bf2f(Sl[(chunk * 64 + i) * SSTR + col]);
  }
  float* op = out + (size_t)(m0 + chunk * 64) * HDIM + n0 + col;
#pragma unroll
  for (int i = 0; i < 64; ++i) {
    h = av * h + bf2f(Sl[(chunk * 64 + 16 + i) * SSTR + col]);
    op[(size_t)i * HDIM] = h;
  }
}

extern "C" void kernel_launch(void* const* d_in, const int* in_sizes, int n_in,
                              void* d_out, int out_size, void* d_ws, size_t ws_size,
                              hipStream_t stream) {
  const float* x = (const float*)d_in[0];   // (T, H)
  const float* a = (const float*)d_in[1];   // (H,)
  const float* B = (const float*)d_in[2];   // (H, H)
  float* out = (float*)d_out;               // (1, T, H) fp32

  uint16_t* xb  = (uint16_t*)d_ws;                                        // 16 MB
  uint16_t* Btb = (uint16_t*)((char*)d_ws + (size_t)16 * 1024 * 1024);    //  8 MB

  // x -> bf16  and  B -> Bt bf16 (fused)
  prep<<<4096 + 1024, 256, 0, stream>>>(x, B, xb, Btb);
  // fused GEMM + recurrence: 256 blocks x 512 threads (8 waves, 64x64 each)
  gemm_scan<<<dim3(HDIM / BN, TDIM / BM), 512, 0, stream>>>(xb, Btb, a, out);
}